// Round 14
// baseline (141.332 us; speedup 1.0000x reference)
//
#include <hip/hip_runtime.h>
#include <math.h>

#define NB 32
#define CIN 32
#define DIM 32
#define KK 5
#define VALID 17
#define CVOL (VALID*VALID*VALID)   // 4913
#define PW 1024                    // plane words (32*32), linear, no padding
#define BUFW (7*PW + 8)            // one cin buffer (+pad for wq7 vb over-read), 16B-aligned
// 2 buffers = 14352 words = 57408 B -> 2 blocks/CU

// ws layout (floats): [0,4000) w_eff ; [4000] B ; [4096, ...) C partials [nsplit][32][4913]

__global__ __launch_bounds__(256) void prep_kernel(const float* __restrict__ weight,
                                                   const float* __restrict__ bias,
                                                   float* __restrict__ ws) {
    int idx = blockIdx.x * 256 + threadIdx.x;
    if (idx < 4000) {
        float s = 0.f;
        #pragma unroll 8
        for (int co = 0; co < 64; ++co) s += weight[co * 4000 + idx];
        ws[idx] = s;
    }
    if (idx == 0) {
        float b = 0.f;
        for (int i = 0; i < 64; ++i) b += bias[i];
        ws[4000] = b;
    }
}

__device__ __forceinline__ void gload_lds16(const float* g, float* l) {
    __builtin_amdgcn_global_load_lds((const __attribute__((address_space(1))) void*)g,
                                     (__attribute__((address_space(3))) void*)l,
                                     16, 0, 0);
}

// Block = (split s, n, d-pair p). 128 threads: dq = tid>>6 (wave), hg = (tid>>3)&7, wq = tid&7.
// Thread outputs: d = 2p+dq; h = 2hg+hh (hg7: h14,15,16); w = 2wq+1, 2wq+2 (+ w=0 if wq==0).
// Slab: TWO linear f32 buffers [7][32][32]; buffer ci&1 read, other staged for cin+1.
// Staging = r12's wave-uniform 1KB global_load_lds chunks (14/wave) — issued BEFORE compute,
// landing under the ~2000-cy compute phase; ONE barrier per cin (T3-lite double buffer).
// NOTE: no min-waves launch-bound arg — (128,4) forced VGPR=64 + scratch spill (round 10, 6x).
// NOTE: staging must stay wave-uniform full-wave 16B/lane — lane<8 per-row variant was 2x slower (r13).
__global__ __launch_bounds__(128) void conv_kernel(const float* __restrict__ x,
                                                   const float* __restrict__ weff,
                                                   float* __restrict__ C,
                                                   int cpS) {
    __shared__ __align__(16) float slab[2 * BUFW];
    const int b = blockIdx.x;
    const int s = b / (NB * 9);
    const int rem = b - s * (NB * 9);
    const int n = rem / 9;
    const int p = rem - n * 9;
    const int tid = threadIdx.x;
    const int dq = tid >> 6;          // wave index
    const int hg = (tid >> 3) & 7;
    const int wq = tid & 7;
    const int lane = tid & 63;
    const int d  = 2 * p + dq;
    const bool dok  = (d < VALID);
    const bool tall = (hg == 7);
    const bool w0t  = (wq == 0);

    // zero both buffers once: OOB planes (never staged) must read as 0
    for (int t = tid; t < (2 * BUFW) / 4; t += 128) ((float4*)slab)[t] = make_float4(0.f, 0.f, 0.f, 0.f);
    __syncthreads();

    const int id0 = 4 * p - 2;
    const int cin0 = s * cpS;
    const size_t xbase = (size_t)n * CIN * (DIM * DIM * DIM);

    // wave-uniform staging: 14 slots/wave, 1KB each (64 lanes x 16B)
    auto stage = [&](float* buf, int cin) {
        const float* xc = x + xbase + (size_t)cin * (DIM * DIM * DIM);
        #pragma unroll
        for (int st = 0; st < 14; ++st) {
            int slot = dq * 14 + st;          // wave-uniform
            int pi = slot >> 2, c = slot & 3;
            int id = id0 + pi;
            if (id >= 0 && id < DIM) {        // wave-uniform guard
                gload_lds16(xc + (size_t)id * PW + c * 256 + lane * 4,
                            buf + pi * PW + c * 256);
            }
        }
    };

    float acc[3][2] = {{0.f,0.f},{0.f,0.f},{0.f,0.f}};
    float accw0[3]  = {0.f, 0.f, 0.f};

    // prologue: stage cin0 into buffer 0
    stage(slab, cin0);
    __syncthreads();

    for (int ci = 0; ci < cpS; ++ci) {
        const float* rdbuf = slab + (ci & 1) * BUFW;
        float*       wrbuf = slab + ((ci & 1) ^ 1) * BUFW;

        // issue next cin's loads first: they complete under this cin's compute
        if (ci + 1 < cpS) stage(wrbuf, cin0 + ci + 1);

        const float* wb = weff + (cin0 + ci) * 125;
        #pragma unroll
        for (int kd = 0; kd < KK; ++kd) {
            const float* plane = rdbuf + (2 * dq + kd) * PW;
            #pragma unroll
            for (int j = 0; j < 9; ++j) {
                const int ih = 4 * hg + j - 2;
                if (((unsigned)ih < 32u) && (j <= 6 || tall)) {
                    const float* rp = plane + ih * 32 + 4 * wq;
                    const float4 va = *(const float4*)rp;
                    const float4 vb = *(const float4*)(rp + 4);  // wq7: guarded below
                    #pragma unroll
                    for (int hh = 0; hh < 3; ++hh) {
                        const int kh = j - 2 * hh;
                        if (kh >= 0 && kh < KK) {
                            if (hh < 2 || tall) {
                                const float w0 = wb[kd * 25 + kh * 5 + 0];
                                const float w1 = wb[kd * 25 + kh * 5 + 1];
                                const float w2 = wb[kd * 25 + kh * 5 + 2];
                                const float w3 = wb[kd * 25 + kh * 5 + 3];
                                const float w4 = wb[kd * 25 + kh * 5 + 4];
                                acc[hh][0] = fmaf(w0, va.x, acc[hh][0]);
                                acc[hh][1] = fmaf(w0, va.z, acc[hh][1]);
                                acc[hh][0] = fmaf(w1, va.y, acc[hh][0]);
                                acc[hh][1] = fmaf(w1, va.w, acc[hh][1]);
                                acc[hh][0] = fmaf(w2, va.z, acc[hh][0]);
                                acc[hh][0] = fmaf(w3, va.w, acc[hh][0]);
                                if (wq < 7) {   // wq7's vb taps are true zero-pad (iw>=32)
                                    acc[hh][0] = fmaf(w4, vb.x, acc[hh][0]);
                                    acc[hh][1] = fmaf(w2, vb.x, acc[hh][1]);
                                    acc[hh][1] = fmaf(w3, vb.y, acc[hh][1]);
                                    acc[hh][1] = fmaf(w4, vb.z, acc[hh][1]);
                                }
                                if (w0t) {      // w=0: kw 2,3,4 hit iw 0,1,2
                                    accw0[hh] = fmaf(w2, va.x, accw0[hh]);
                                    accw0[hh] = fmaf(w3, va.y, accw0[hh]);
                                    accw0[hh] = fmaf(w4, va.z, accw0[hh]);
                                }
                            }
                        }
                    }
                }
            }
        }
        __syncthreads();   // staged loads drained + WAR for next overwrite
    }

    if (dok) {
        float* Cn = C + ((size_t)s * NB + n) * CVOL + (size_t)d * (VALID * VALID);
        #pragma unroll
        for (int hh = 0; hh < 3; ++hh) {
            if (hh < 2 || tall) {
                int h = 2 * hg + hh;
                Cn[h * VALID + 2 * wq + 1] = acc[hh][0];
                Cn[h * VALID + 2 * wq + 2] = acc[hh][1];
                if (w0t) Cn[h * VALID] = accw0[hh];
            }
        }
    }
}

// Blocks 0..863: one wave per active cell (n, i<3, j<3, k<3); lane = p1-subcell;
// fused nsplit reduction; butterfly sum. Blocks 864..988: constant fill.
__global__ __launch_bounds__(64) void pool_kernel(const float* __restrict__ C,
                                                  const float* __restrict__ wsB,
                                                  float* __restrict__ out,
                                                  int nsplit) {
    const int b = blockIdx.x;
    const int l = threadIdx.x;
    const float B = wsB[0];

    if (b < 864) {
        const int n = b / 27;
        const int cell = b - n * 27;
        const int ci = cell / 9, cj = (cell / 3) % 3, ck = cell % 3;
        float v = 0.f;
        if (l < 27) {
            const int da = l / 9, db = (l / 3) % 3, dc = l % 3;
            const int pz = 3 * ci + da, py = 3 * cj + db, px = 3 * ck + dc;
            const float* Cn = C + (size_t)n * CVOL;
            float m = -INFINITY;
            #pragma unroll
            for (int dz = 0; dz < 2; ++dz)
            #pragma unroll
            for (int dy = 0; dy < 2; ++dy)
            #pragma unroll
            for (int dx = 0; dx < 2; ++dx) {
                int z = 2 * pz + dz, y = 2 * py + dy, xx = 2 * px + dx;
                float t;
                if (z < VALID && y < VALID && xx < VALID) {
                    size_t off = ((size_t)z * VALID + y) * VALID + xx;
                    float sum = 0.f;
                    for (int ss = 0; ss < nsplit; ++ss)
                        sum += Cn[(size_t)ss * NB * CVOL + off];
                    t = sum + B;
                } else {
                    t = B;
                }
                m = fmaxf(m, t);
            }
            v = m;
        }
        #pragma unroll
        for (int off = 32; off > 0; off >>= 1) v += __shfl_xor(v, off, 64);
        if (l == 0) out[n * 1000 + ci * 100 + cj * 10 + ck] = v;
    } else {
        const int fb = b - 864;           // 0..124
        #pragma unroll
        for (int t = 0; t < 4; ++t) {
            int idx = fb * 256 + 64 * t + l;
            if (idx < 32000) {
                int r = idx % 1000;
                int i = r / 100, j = (r / 10) % 10, k = r % 10;
                if (i >= 3 || j >= 3 || k >= 3) out[idx] = 27.f * B;
            }
        }
    }
}

extern "C" void kernel_launch(void* const* d_in, const int* in_sizes, int n_in,
                              void* d_out, int out_size, void* d_ws, size_t ws_size,
                              hipStream_t stream) {
    const float* x      = (const float*)d_in[0];
    const float* weight = (const float*)d_in[1];
    const float* bias   = (const float*)d_in[2];
    float* out = (float*)d_out;
    float* ws  = (float*)d_ws;
    float* weff = ws;
    float* wsB  = ws + 4000;
    float* C    = ws + 4096;

    int nsplit = 1;
    if      (ws_size >= (size_t)(4096 + 8 * NB * CVOL) * 4) nsplit = 8;
    else if (ws_size >= (size_t)(4096 + 4 * NB * CVOL) * 4) nsplit = 4;
    else if (ws_size >= (size_t)(4096 + 2 * NB * CVOL) * 4) nsplit = 2;
    int cpS = CIN / nsplit;

    prep_kernel<<<dim3(16), dim3(256), 0, stream>>>(weight, bias, ws);
    conv_kernel<<<dim3(nsplit * NB * 9), dim3(128), 0, stream>>>(x, weff, C, cpS);
    pool_kernel<<<dim3(989), dim3(64), 0, stream>>>(C, wsB, out, nsplit);
}

// Round 16
// 91.591 us; speedup vs baseline: 1.5431x; 1.5431x over previous
//
#include <hip/hip_runtime.h>
#include <math.h>

#define NB 32
#define CIN 32
#define DIM 32
#define KK 5
#define VALID 17
#define CVOL (VALID*VALID*VALID)   // 4913
#define PW 1024                    // plane words (32*32), linear, no padding
#define SLABF (7*PW + 4)           // +4 pad words (legacy; vb no longer read from LDS)

// ws layout (floats): [0,4000) w_eff ; [4000] B ; [4096, ...) C partials [nsplit][32][4913]

__global__ __launch_bounds__(256) void prep_kernel(const float* __restrict__ weight,
                                                   const float* __restrict__ bias,
                                                   float* __restrict__ ws) {
    int idx = blockIdx.x * 256 + threadIdx.x;
    if (idx < 4000) {
        float s = 0.f;
        #pragma unroll 8
        for (int co = 0; co < 64; ++co) s += weight[co * 4000 + idx];
        ws[idx] = s;
    }
    if (idx == 0) {
        float b = 0.f;
        for (int i = 0; i < 64; ++i) b += bias[i];
        ws[4000] = b;
    }
}

__device__ __forceinline__ void gload_lds16(const float* g, float* l) {
    __builtin_amdgcn_global_load_lds((const __attribute__((address_space(1))) void*)g,
                                     (__attribute__((address_space(3))) void*)l,
                                     16, 0, 0);
}

// shfl_down-by-1: lane i <- lane i+1. row_shl:1 (0x101) — the shfl_down lowering in
// LLVM/rocPRIM (row_shr is shfl_up; r15 used it and failed absmax=108 — direction matters).
// Lanes 15/31/47/63 source across the row boundary -> 0 via bound_ctrl (all wq=7, masked anyway).
__device__ __forceinline__ float dpp_shl1(float v) {
    return __int_as_float(__builtin_amdgcn_update_dpp(0, __float_as_int(v),
                                                      0x101 /*row_shl:1*/, 0xF, 0xF, true));
}

// Block = (split s, n, d-pair p). 128 threads: dq = tid>>6 (wave), hg = (tid>>3)&7, wq = tid&7.
// Thread outputs: d = 2p+dq; h = 2hg+hh (hg7: h14,15,16); w = 2wq+1, 2wq+2 (+ w=0 if wq==0).
// Slab: LINEAR f32 [pi 7][ih 32][iw 32]; pi = id-(4p-2); kd plane: pi = 2dq+kd.
// Staging: r12's wave-uniform 1KB global_load_lds (14 slots/wave) — verified best (r13/r14 worse).
// r16: vb (floats 4wq+4..4wq+6) = va of lane wq+1 via DPP row_shl:1 — halves ds_read_b128
// (90->45 per wave-cin). wq7 lanes' DPP garbage masked by the wq<7 guard (true taps are zero-pad);
// 8-group-uniform predicates keep the source lane active whenever the dest lane is.
// NOTE: no min-waves launch-bound arg — (128,4) forced VGPR=64 + scratch spill (round 10, 6x).
__global__ __launch_bounds__(128) void conv_kernel(const float* __restrict__ x,
                                                   const float* __restrict__ weff,
                                                   float* __restrict__ C,
                                                   int cpS) {
    __shared__ __align__(16) float slab[SLABF];
    const int b = blockIdx.x;
    const int s = b / (NB * 9);
    const int rem = b - s * (NB * 9);
    const int n = rem / 9;
    const int p = rem - n * 9;
    const int tid = threadIdx.x;
    const int dq = tid >> 6;          // wave index
    const int hg = (tid >> 3) & 7;
    const int wq = tid & 7;
    const int lane = tid & 63;
    const int d  = 2 * p + dq;
    const bool dok  = (d < VALID);
    const bool tall = (hg == 7);
    const bool w0t  = (wq == 0);

    // zero slab once: OOB planes (never staged) must read as 0
    for (int t = tid; t < SLABF / 4; t += 128) ((float4*)slab)[t] = make_float4(0.f, 0.f, 0.f, 0.f);
    __syncthreads();

    const int id0 = 4 * p - 2;
    const int cin0 = s * cpS;

    float acc[3][2] = {{0.f,0.f},{0.f,0.f},{0.f,0.f}};
    float accw0[3]  = {0.f, 0.f, 0.f};

    for (int ci = 0; ci < cpS; ++ci) {
        // stage: 28 slots (7 planes x 4 chunks of 1KB); wave wv issues slots [14wv,14wv+14)
        const float* xc = x + ((size_t)n * CIN + (cin0 + ci)) * (DIM * DIM * DIM);
        #pragma unroll
        for (int st = 0; st < 14; ++st) {
            int slot = dq * 14 + st;          // wave-uniform
            int pi = slot >> 2, c = slot & 3;
            int id = id0 + pi;
            if (id >= 0 && id < DIM) {        // wave-uniform guard
                gload_lds16(xc + (size_t)id * PW + c * 256 + lane * 4,
                            slab + pi * PW + c * 256);
            }
        }
        __syncthreads();   // drains vmcnt: staged data visible

        const float* wb = weff + (cin0 + ci) * 125;
        #pragma unroll
        for (int kd = 0; kd < KK; ++kd) {
            const float* plane = slab + (2 * dq + kd) * PW;
            #pragma unroll
            for (int j = 0; j < 9; ++j) {
                const int ih = 4 * hg + j - 2;
                if (((unsigned)ih < 32u) && (j <= 6 || tall)) {
                    const float4 va = *(const float4*)(plane + ih * 32 + 4 * wq);
                    const float vb0 = dpp_shl1(va.x);   // float 4wq+4 (lane wq+1's va.x)
                    const float vb1 = dpp_shl1(va.y);   // float 4wq+5
                    const float vb2 = dpp_shl1(va.z);   // float 4wq+6
                    #pragma unroll
                    for (int hh = 0; hh < 3; ++hh) {
                        const int kh = j - 2 * hh;
                        if (kh >= 0 && kh < KK) {
                            if (hh < 2 || tall) {
                                const float w0 = wb[kd * 25 + kh * 5 + 0];
                                const float w1 = wb[kd * 25 + kh * 5 + 1];
                                const float w2 = wb[kd * 25 + kh * 5 + 2];
                                const float w3 = wb[kd * 25 + kh * 5 + 3];
                                const float w4 = wb[kd * 25 + kh * 5 + 4];
                                acc[hh][0] = fmaf(w0, va.x, acc[hh][0]);
                                acc[hh][1] = fmaf(w0, va.z, acc[hh][1]);
                                acc[hh][0] = fmaf(w1, va.y, acc[hh][0]);
                                acc[hh][1] = fmaf(w1, va.w, acc[hh][1]);
                                acc[hh][0] = fmaf(w2, va.z, acc[hh][0]);
                                acc[hh][0] = fmaf(w3, va.w, acc[hh][0]);
                                if (wq < 7) {   // wq7's vb taps are true zero-pad (iw>=32)
                                    acc[hh][0] = fmaf(w4, vb0, acc[hh][0]);
                                    acc[hh][1] = fmaf(w2, vb0, acc[hh][1]);
                                    acc[hh][1] = fmaf(w3, vb1, acc[hh][1]);
                                    acc[hh][1] = fmaf(w4, vb2, acc[hh][1]);
                                }
                                if (w0t) {      // w=0: kw 2,3,4 hit iw 0,1,2
                                    accw0[hh] = fmaf(w2, va.x, accw0[hh]);
                                    accw0[hh] = fmaf(w3, va.y, accw0[hh]);
                                    accw0[hh] = fmaf(w4, va.z, accw0[hh]);
                                }
                            }
                        }
                    }
                }
            }
        }
        __syncthreads();   // WAR: next stage overwrites slab
    }

    if (dok) {
        float* Cn = C + ((size_t)s * NB + n) * CVOL + (size_t)d * (VALID * VALID);
        #pragma unroll
        for (int hh = 0; hh < 3; ++hh) {
            if (hh < 2 || tall) {
                int h = 2 * hg + hh;
                Cn[h * VALID + 2 * wq + 1] = acc[hh][0];
                Cn[h * VALID + 2 * wq + 2] = acc[hh][1];
                if (w0t) Cn[h * VALID] = accw0[hh];
            }
        }
    }
}

// Blocks 0..863: one wave per active cell (n, i<3, j<3, k<3); lane = p1-subcell;
// fused nsplit reduction; butterfly sum. Blocks 864..988: constant fill.
__global__ __launch_bounds__(64) void pool_kernel(const float* __restrict__ C,
                                                  const float* __restrict__ wsB,
                                                  float* __restrict__ out,
                                                  int nsplit) {
    const int b = blockIdx.x;
    const int l = threadIdx.x;
    const float B = wsB[0];

    if (b < 864) {
        const int n = b / 27;
        const int cell = b - n * 27;
        const int ci = cell / 9, cj = (cell / 3) % 3, ck = cell % 3;
        float v = 0.f;
        if (l < 27) {
            const int da = l / 9, db = (l / 3) % 3, dc = l % 3;
            const int pz = 3 * ci + da, py = 3 * cj + db, px = 3 * ck + dc;
            const float* Cn = C + (size_t)n * CVOL;
            float m = -INFINITY;
            #pragma unroll
            for (int dz = 0; dz < 2; ++dz)
            #pragma unroll
            for (int dy = 0; dy < 2; ++dy)
            #pragma unroll
            for (int dx = 0; dx < 2; ++dx) {
                int z = 2 * pz + dz, y = 2 * py + dy, xx = 2 * px + dx;
                float t;
                if (z < VALID && y < VALID && xx < VALID) {
                    size_t off = ((size_t)z * VALID + y) * VALID + xx;
                    float sum = 0.f;
                    for (int ss = 0; ss < nsplit; ++ss)
                        sum += Cn[(size_t)ss * NB * CVOL + off];
                    t = sum + B;
                } else {
                    t = B;
                }
                m = fmaxf(m, t);
            }
            v = m;
        }
        #pragma unroll
        for (int off = 32; off > 0; off >>= 1) v += __shfl_xor(v, off, 64);
        if (l == 0) out[n * 1000 + ci * 100 + cj * 10 + ck] = v;
    } else {
        const int fb = b - 864;           // 0..124
        #pragma unroll
        for (int t = 0; t < 4; ++t) {
            int idx = fb * 256 + 64 * t + l;
            if (idx < 32000) {
                int r = idx % 1000;
                int i = r / 100, j = (r / 10) % 10, k = r % 10;
                if (i >= 3 || j >= 3 || k >= 3) out[idx] = 27.f * B;
            }
        }
    }
}

extern "C" void kernel_launch(void* const* d_in, const int* in_sizes, int n_in,
                              void* d_out, int out_size, void* d_ws, size_t ws_size,
                              hipStream_t stream) {
    const float* x      = (const float*)d_in[0];
    const float* weight = (const float*)d_in[1];
    const float* bias   = (const float*)d_in[2];
    float* out = (float*)d_out;
    float* ws  = (float*)d_ws;
    float* weff = ws;
    float* wsB  = ws + 4000;
    float* C    = ws + 4096;

    int nsplit = 1;
    if      (ws_size >= (size_t)(4096 + 8 * NB * CVOL) * 4) nsplit = 8;
    else if (ws_size >= (size_t)(4096 + 4 * NB * CVOL) * 4) nsplit = 4;
    else if (ws_size >= (size_t)(4096 + 2 * NB * CVOL) * 4) nsplit = 2;
    int cpS = CIN / nsplit;

    prep_kernel<<<dim3(16), dim3(256), 0, stream>>>(weight, bias, ws);
    conv_kernel<<<dim3(nsplit * NB * 9), dim3(128), 0, stream>>>(x, weff, C, cpS);
    pool_kernel<<<dim3(989), dim3(64), 0, stream>>>(C, wsB, out, nsplit);
}